// Round 9
// baseline (404.355 us; speedup 1.0000x reference)
//
#include <hip/hip_runtime.h>

#define B_ 8
#define T_ 2048
#define E_ 256
#define H_ 8
#define DH_ 32
#define SCALING_ 0.17677669529663687f   // 1/sqrt(32)
#define LOG2E_ 1.4426950408889634f
// Q is pre-scaled by SCALING*log2(e): scores exit QK in log2 domain -> hw exp2
#define QSCALE_ (SCALING_ * LOG2E_)

typedef short bf16x8 __attribute__((ext_vector_type(8)));   // 8 bf16 in 4 VGPRs
typedef float floatx4 __attribute__((ext_vector_type(4)));

__device__ __forceinline__ unsigned short f2bf(float f) {
    union { float f; unsigned u; } v; v.f = f;
    unsigned r = v.u + 0x7FFFu + ((v.u >> 16) & 1u);   // RNE
    return (unsigned short)(r >> 16);
}

// pack 2 f32 -> 2 bf16 (round-half-up) in 3 VALU: add, add, v_perm_b32
__device__ __forceinline__ unsigned pk2(float a, float b) {
    union { float f; unsigned u; } ua, ub;
    ua.f = a; ub.f = b;
    return __builtin_amdgcn_perm(ub.u + 0x8000u, ua.u + 0x8000u, 0x07060302u);
}

__device__ __forceinline__ float fexp2(float x) {
#if __has_builtin(__builtin_amdgcn_exp2f)
    return __builtin_amdgcn_exp2f(x);
#else
    return exp2f(x);
#endif
}

__device__ __forceinline__ bf16x8 pack8(float4 a, float4 b) {
    bf16x8 o;
    o[0] = (short)f2bf(a.x); o[1] = (short)f2bf(a.y);
    o[2] = (short)f2bf(a.z); o[3] = (short)f2bf(a.w);
    o[4] = (short)f2bf(b.x); o[5] = (short)f2bf(b.y);
    o[6] = (short)f2bf(b.z); o[7] = (short)f2bf(b.w);
    return o;
}

// ---------------------------------------------------------------------------
// Kernel 0: weight prepack fp32 -> bf16 (tiny: 128 blocks).
// ---------------------------------------------------------------------------
__global__ __launch_bounds__(256) void prepack_kernel(
    const float* __restrict__ Wq, const float* __restrict__ Wk,
    const float* __restrict__ Wv, const float* __restrict__ Wo,
    unsigned short* __restrict__ Wpack) {
    int idx = blockIdx.x * 256 + threadIdx.x;   // 32768 threads
    int m = idx >> 13;                           // matrix id 0..3
    int e = (idx & 8191) * 8;
    const float* W = (m == 0) ? Wq : (m == 1) ? Wk : (m == 2) ? Wv : Wo;
    float4 a = ((const float4*)(W + e))[0];
    float4 b = ((const float4*)(W + e))[1];
    *(bf16x8*)(Wpack + (size_t)m * 65536 + e) = pack8(a, b);
}

// ---------------------------------------------------------------------------
// Kernel 1: QKV projection (blocks 0..1535) FUSED with mask nonzero check
// (blocks 1536..3583) — the 128 MB mask scan overlaps the GEMM.
// ---------------------------------------------------------------------------
__global__ __launch_bounds__(256, 4) void qkvmask_kernel(
    const float* __restrict__ hs, const float* __restrict__ oq,
    const unsigned short* __restrict__ Wpack,
    const float* __restrict__ bq, const float* __restrict__ bk,
    const float* __restrict__ bv,
    unsigned short* __restrict__ Qw, unsigned short* __restrict__ Kw,
    unsigned short* __restrict__ Vtw,
    const int* __restrict__ mask, int* __restrict__ mask_nz) {
    if (blockIdx.x >= 1536) {
        const size_t n4 = (size_t)B_ * T_ * T_ / 4;   // 8,388,608 int4
        size_t gid = (size_t)(blockIdx.x - 1536) * 256 + threadIdx.x;
        int acc = 0;
        for (size_t i = gid; i < n4; i += (size_t)2048 * 256) {
            int4 v = ((const int4*)mask)[i];
            acc |= v.x | v.y | v.z | v.w;
        }
        if (__builtin_amdgcn_ballot_w64(acc != 0)) {
            if ((threadIdx.x & 63) == 0) atomicOr(mask_nz, 1);
        }
        return;
    }
    __shared__ __align__(16) unsigned short sX[32][264];
    const int mat = blockIdx.x >> 9;          // 0=Q, 1=K, 2=V
    const int mbase = (blockIdx.x & 511) * 32;
    const int b = mbase >> 11, tbase = mbase & 2047;
    const int tid = threadIdx.x;

#pragma unroll
    for (int i = 0; i < 8; ++i) {
        int idx = tid + i * 256;
        int row = idx >> 6, c4 = idx & 63;
        float4 hv = ((const float4*)(hs + (size_t)(mbase + row) * E_))[c4];
        if (mat < 2) {
            float4 ov = ((const float4*)(oq + (size_t)(mbase + row) * E_))[c4];
            hv.x += ov.x; hv.y += ov.y; hv.z += ov.z; hv.w += ov.w;
        }
        ushort4 pb;
        pb.x = f2bf(hv.x); pb.y = f2bf(hv.y); pb.z = f2bf(hv.z); pb.w = f2bf(hv.w);
        *(ushort4*)&sX[row][c4 * 4] = pb;
    }
    __syncthreads();

    const int wave = tid >> 6, lane = tid & 63;
    const int quad = lane >> 4, m16 = lane & 15;
    const unsigned short* W = Wpack + (size_t)mat * 65536;

    bf16x8 xf[2][8];
#pragma unroll
    for (int hgrp = 0; hgrp < 2; ++hgrp)
#pragma unroll
        for (int kc = 0; kc < 8; ++kc)
            xf[hgrp][kc] = *(const bf16x8*)&sX[hgrp * 16 + m16][kc * 32 + quad * 8];

    if (mat < 2) {
        const float* bias = (mat == 0) ? bq : bk;
        unsigned short* Out = (mat == 0) ? Qw : Kw;
#pragma unroll
        for (int i = 0; i < 4; ++i) {
            int nt = wave * 4 + i;
            int ecol = nt * 16 + m16;
            const unsigned short* wrow = W + (size_t)ecol * E_;
            floatx4 acc0 = {0.f, 0.f, 0.f, 0.f};
            floatx4 acc1 = {0.f, 0.f, 0.f, 0.f};
#pragma unroll
            for (int kc = 0; kc < 8; ++kc) {
                bf16x8 bf = *(const bf16x8*)(wrow + kc * 32 + quad * 8);
                acc0 = __builtin_amdgcn_mfma_f32_16x16x32_bf16(xf[0][kc], bf, acc0, 0, 0, 0);
                acc1 = __builtin_amdgcn_mfma_f32_16x16x32_bf16(xf[1][kc], bf, acc1, 0, 0, 0);
            }
            float bs = bias[ecol];
            int h = ecol >> 5, dh = ecol & 31;
            size_t base0 = (((size_t)b * H_ + h) * T_ + (tbase + quad * 4)) * DH_ + dh;
            size_t base1 = base0 + (size_t)16 * DH_;
#pragma unroll
            for (int r = 0; r < 4; ++r) {
                float v0 = acc0[r] + bs, v1 = acc1[r] + bs;
                if (mat == 0) { v0 *= QSCALE_; v1 *= QSCALE_; }
                Out[base0 + (size_t)r * DH_] = f2bf(v0);
                Out[base1 + (size_t)r * DH_] = f2bf(v1);
            }
        }
    } else {
#pragma unroll
        for (int i = 0; i < 4; ++i) {
            int et = wave * 4 + i;
            int erow = et * 16 + m16;
            const unsigned short* wrow = W + (size_t)erow * E_;
            floatx4 acc0 = {0.f, 0.f, 0.f, 0.f};
            floatx4 acc1 = {0.f, 0.f, 0.f, 0.f};
#pragma unroll
            for (int kc = 0; kc < 8; ++kc) {
                bf16x8 wf = *(const bf16x8*)(wrow + kc * 32 + quad * 8);
                acc0 = __builtin_amdgcn_mfma_f32_16x16x32_bf16(wf, xf[0][kc], acc0, 0, 0, 0);
                acc1 = __builtin_amdgcn_mfma_f32_16x16x32_bf16(wf, xf[1][kc], acc1, 0, 0, 0);
            }
            int t0 = tbase + m16, t1 = t0 + 16;
#pragma unroll
            for (int r = 0; r < 4; ++r) {
                int ev = et * 16 + quad * 4 + r;
                int h = ev >> 5, dh = ev & 31;
                size_t vb = (((size_t)b * H_ + h) * DH_ + dh) * T_;
                Vtw[vb + t0] = f2bf(acc0[r] + bv[ev]);
                Vtw[vb + t1] = f2bf(acc1[r] + bv[ev]);
            }
        }
    }
}

// ---------------------------------------------------------------------------
// Kernel 2: flash attention, S^T form, two q-streams per wave, 128-thr blocks.
// __launch_bounds__(128,3): 170-reg cap — R8's (128,4) forced a 64-arch-reg
// split and spilled ~55 MB/launch to scratch (WRITE_SIZE 8->51 MB).
// Fast path is tile-pipelined: V for the whole 128-key tile prefetched at
// tile top; QK(h1) overlaps h0's LDS-write latency; single batched P read +
// 24-MFMA PV burst per tile (one LDS turnaround per tile instead of two).
// Slow path (mask!=0) keeps per-half online softmax (rescale ordering).
// No barriers (sPT per-wave). Grid = B*H*(T/64) = 2048 blocks.
// ---------------------------------------------------------------------------
__global__ __launch_bounds__(128, 3) void attn_kernel(
    const unsigned short* __restrict__ Qw, const unsigned short* __restrict__ Kw,
    const unsigned short* __restrict__ Vtw, const float* __restrict__ mask,
    const int* __restrict__ mask_nz, unsigned short* __restrict__ attnw) {
    __shared__ __align__(16) unsigned short sPT[2][2][16][136];  // [wave][stream][q][key]
    const int tid = threadIdx.x;
    const int wave = tid >> 6, lane = tid & 63;
    const int quad = lane >> 4, m16 = lane & 15;
    const int bh = blockIdx.x & 63, qt = blockIdx.x >> 6;   // bh%8==h -> XCD
    const int b = bh >> 3, h = bh & 7;
    const int qA = qt * 64 + wave * 32;
    const int qB = qA + 16;
    const int mnz = *mask_nz;

    bf16x8 qfragA = *(const bf16x8*)(Qw + ((size_t)bh * T_ + qA + m16) * DH_ + quad * 8);
    bf16x8 qfragB = *(const bf16x8*)(Qw + ((size_t)bh * T_ + qB + m16) * DH_ + quad * 8);
    const unsigned short* Kb = Kw + (size_t)bh * T_ * DH_;
    const unsigned short* Vb = Vtw + (size_t)bh * DH_ * T_;
    const float* MbA = mask + ((size_t)b * T_ + qA + m16) * T_ + quad * 4;
    const float* MbB = MbA + (size_t)16 * T_;

    floatx4 O0A = {0.f, 0.f, 0.f, 0.f}, O1A = {0.f, 0.f, 0.f, 0.f};
    floatx4 O0B = {0.f, 0.f, 0.f, 0.f}, O1B = {0.f, 0.f, 0.f, 0.f};
    floatx4 LA  = {0.f, 0.f, 0.f, 0.f}, LB  = {0.f, 0.f, 0.f, 0.f};
    float mprevA = -1e30f, mprevB = -1e30f;
    const floatx4 zero = {0.f, 0.f, 0.f, 0.f};

    bf16x8 ones8;
#pragma unroll
    for (int i = 0; i < 8; ++i) ones8[i] = (short)0x3F80;   // bf16 1.0

    bf16x8 kf[8];
#pragma unroll
    for (int c = 0; c < 8; ++c)
        kf[c] = *(const bf16x8*)(Kb + (size_t)(c * 16 + m16) * DH_ + quad * 8);

    for (int kt = 0; kt < 16; ++kt) {
        const int s0 = kt * 128;
        // V prefetch for the whole tile (8 b128) — max distance before PV.
        bf16x8 vf0[4], vf1[4];
#pragma unroll
        for (int j = 0; j < 4; ++j) {
            int ko = s0 + j * 32 + quad * 8;
            vf0[j] = *(const bf16x8*)(Vb + (size_t)m16 * T_ + ko);
            vf1[j] = *(const bf16x8*)(Vb + (size_t)(16 + m16) * T_ + ko);
        }
        if (!mnz) {
            // ---- FAST PATH: tile-pipelined ----
#pragma unroll
            for (int hf = 0; hf < 2; ++hf) {
                const int cb = hf * 4;
                floatx4 scA[4], scB[4];
#pragma unroll
                for (int c = 0; c < 4; ++c) {
                    scA[c] = __builtin_amdgcn_mfma_f32_16x16x32_bf16(kf[cb + c], qfragA, zero, 0, 0, 0);
                    scB[c] = __builtin_amdgcn_mfma_f32_16x16x32_bf16(kf[cb + c], qfragB, zero, 0, 0, 0);
                }
                if (kt < 15) {
#pragma unroll
                    for (int c = 0; c < 4; ++c)
                        kf[cb + c] = *(const bf16x8*)(
                            Kb + (size_t)(s0 + 128 + (cb + c) * 16 + m16) * DH_ + quad * 8);
                }
#pragma unroll
                for (int c = 0; c < 4; ++c) {
                    float a0 = fexp2(scA[c][0]), a1 = fexp2(scA[c][1]);
                    float a2 = fexp2(scA[c][2]), a3 = fexp2(scA[c][3]);
                    float b0 = fexp2(scB[c][0]), b1 = fexp2(scB[c][1]);
                    float b2 = fexp2(scB[c][2]), b3 = fexp2(scB[c][3]);
                    uint2 wa = {pk2(a0, a1), pk2(a2, a3)};
                    uint2 wb = {pk2(b0, b1), pk2(b2, b3)};
                    int col = (cb + c) * 16 + quad * 4;
                    *(uint2*)&sPT[wave][0][m16][col] = wa;
                    *(uint2*)&sPT[wave][1][m16][col] = wb;
                }
            }
            // Batched P read + PV burst (h1's QK/exp hid h0's write latency).
#pragma unroll
            for (int sb = 0; sb < 4; ++sb) {
                int col = sb * 32 + quad * 8;
                bf16x8 pbA = *(const bf16x8*)&sPT[wave][0][m16][col];
                bf16x8 pbB = *(const bf16x8*)&sPT[wave][1][m16][col];
                O0A = __builtin_amdgcn_mfma_f32_16x16x32_bf16(vf0[sb], pbA, O0A, 0, 0, 0);
                O0B = __builtin_amdgcn_mfma_f32_16x16x32_bf16(vf0[sb], pbB, O0B, 0, 0, 0);
                O1A = __builtin_amdgcn_mfma_f32_16x16x32_bf16(vf1[sb], pbA, O1A, 0, 0, 0);
                O1B = __builtin_amdgcn_mfma_f32_16x16x32_bf16(vf1[sb], pbB, O1B, 0, 0, 0);
                LA  = __builtin_amdgcn_mfma_f32_16x16x32_bf16(ones8, pbA, LA, 0, 0, 0);
                LB  = __builtin_amdgcn_mfma_f32_16x16x32_bf16(ones8, pbB, LB, 0, 0, 0);
            }
        } else {
            // ---- SLOW PATH: per-half online softmax (rescale ordering) ----
#pragma unroll
            for (int hf = 0; hf < 2; ++hf) {
                const int cb = hf * 4;
                floatx4 scA[4], scB[4];
#pragma unroll
                for (int c = 0; c < 4; ++c) {
                    scA[c] = __builtin_amdgcn_mfma_f32_16x16x32_bf16(kf[cb + c], qfragA, zero, 0, 0, 0);
                    scB[c] = __builtin_amdgcn_mfma_f32_16x16x32_bf16(kf[cb + c], qfragB, zero, 0, 0, 0);
                }
                if (kt < 15) {
#pragma unroll
                    for (int c = 0; c < 4; ++c)
                        kf[cb + c] = *(const bf16x8*)(
                            Kb + (size_t)(s0 + 128 + (cb + c) * 16 + m16) * DH_ + quad * 8);
                }
#pragma unroll
                for (int c = 0; c < 4; ++c) {
                    float4 ma = *(const float4*)(MbA + s0 + (cb + c) * 16);
                    float4 mb = *(const float4*)(MbB + s0 + (cb + c) * 16);
                    scA[c][0] += ma.x * LOG2E_; scA[c][1] += ma.y * LOG2E_;
                    scA[c][2] += ma.z * LOG2E_; scA[c][3] += ma.w * LOG2E_;
                    scB[c][0] += mb.x * LOG2E_; scB[c][1] += mb.y * LOG2E_;
                    scB[c][2] += mb.z * LOG2E_; scB[c][3] += mb.w * LOG2E_;
                }
                float mlA = -1e30f, mlB = -1e30f;
#pragma unroll
                for (int c = 0; c < 4; ++c) {
                    mlA = fmaxf(fmaxf(fmaxf(scA[c][0], scA[c][1]), fmaxf(scA[c][2], scA[c][3])), mlA);
                    mlB = fmaxf(fmaxf(fmaxf(scB[c][0], scB[c][1]), fmaxf(scB[c][2], scB[c][3])), mlB);
                }
                mlA = fmaxf(mlA, __shfl_xor(mlA, 16, 64));
                mlA = fmaxf(mlA, __shfl_xor(mlA, 32, 64));
                mlB = fmaxf(mlB, __shfl_xor(mlB, 16, 64));
                mlB = fmaxf(mlB, __shfl_xor(mlB, 32, 64));
                float mnA = fmaxf(mprevA, mlA), mnB = fmaxf(mprevB, mlB);
                float alA = fexp2(mprevA - mnA), alB = fexp2(mprevB - mnB);
                mprevA = mnA; mprevB = mnB;
#pragma unroll
                for (int r = 0; r < 4; ++r) {
                    O0A[r] *= alA; O1A[r] *= alA; LA[r] *= alA;
                    O0B[r] *= alB; O1B[r] *= alB; LB[r] *= alB;
                }
#pragma unroll
                for (int c = 0; c < 4; ++c) {
                    float a0 = fexp2(scA[c][0] - mnA), a1 = fexp2(scA[c][1] - mnA);
                    float a2 = fexp2(scA[c][2] - mnA), a3 = fexp2(scA[c][3] - mnA);
                    float b0 = fexp2(scB[c][0] - mnB), b1 = fexp2(scB[c][1] - mnB);
                    float b2 = fexp2(scB[c][2] - mnB), b3 = fexp2(scB[c][3] - mnB);
                    uint2 wa = {pk2(a0, a1), pk2(a2, a3)};
                    uint2 wb = {pk2(b0, b1), pk2(b2, b3)};
                    int col = (cb + c) * 16 + quad * 4;
                    *(uint2*)&sPT[wave][0][m16][col] = wa;
                    *(uint2*)&sPT[wave][1][m16][col] = wb;
                }
                // PV for this half (must precede next max update)
#pragma unroll
                for (int sb2 = 0; sb2 < 2; ++sb2) {
                    int j = hf * 2 + sb2;
                    int col = j * 32 + quad * 8;
                    bf16x8 pbA = *(const bf16x8*)&sPT[wave][0][m16][col];
                    bf16x8 pbB = *(const bf16x8*)&sPT[wave][1][m16][col];
                    O0A = __builtin_amdgcn_mfma_f32_16x16x32_bf16(vf0[j], pbA, O0A, 0, 0, 0);
                    O0B = __builtin_amdgcn_mfma_f32_16x16x32_bf16(vf0[j], pbB, O0B, 0, 0, 0);
                    O1A = __builtin_amdgcn_mfma_f32_16x16x32_bf16(vf1[j], pbA, O1A, 0, 0, 0);
                    O1B = __builtin_amdgcn_mfma_f32_16x16x32_bf16(vf1[j], pbB, O1B, 0, 0, 0);
                    LA  = __builtin_amdgcn_mfma_f32_16x16x32_bf16(ones8, pbA, LA, 0, 0, 0);
                    LB  = __builtin_amdgcn_mfma_f32_16x16x32_bf16(ones8, pbB, LB, 0, 0, 0);
                }
            }
        }
    }
    float invA = 1.0f / LA[0], invB = 1.0f / LB[0];
    size_t obA = ((size_t)b * T_ + qA + m16) * E_ + h * DH_ + quad * 4;
    size_t obB = ((size_t)b * T_ + qB + m16) * E_ + h * DH_ + quad * 4;
    ushort4 sv;
    sv.x = f2bf(O0A[0] * invA); sv.y = f2bf(O0A[1] * invA);
    sv.z = f2bf(O0A[2] * invA); sv.w = f2bf(O0A[3] * invA);
    *(ushort4*)(attnw + obA) = sv;
    sv.x = f2bf(O1A[0] * invA); sv.y = f2bf(O1A[1] * invA);
    sv.z = f2bf(O1A[2] * invA); sv.w = f2bf(O1A[3] * invA);
    *(ushort4*)(attnw + obA + 16) = sv;
    sv.x = f2bf(O0B[0] * invB); sv.y = f2bf(O0B[1] * invB);
    sv.z = f2bf(O0B[2] * invB); sv.w = f2bf(O0B[3] * invB);
    *(ushort4*)(attnw + obB) = sv;
    sv.x = f2bf(O1B[0] * invB); sv.y = f2bf(O1B[1] * invB);
    sv.z = f2bf(O1B[2] * invB); sv.w = f2bf(O1B[3] * invB);
    *(ushort4*)(attnw + obB + 16) = sv;
}

// ---------------------------------------------------------------------------
// Kernel 3: output projection: out = attn @ Wo^T + bo  (fp32 out, bf16 weights)
// ---------------------------------------------------------------------------
__global__ __launch_bounds__(256, 4) void oproj_kernel(
    const unsigned short* __restrict__ attnw, const unsigned short* __restrict__ Wob,
    const float* __restrict__ bo, float* __restrict__ out) {
    __shared__ __align__(16) unsigned short sA[16][264];
    const int tid = threadIdx.x;
    const int mbase = blockIdx.x * 16;
#pragma unroll
    for (int i = 0; i < 4; ++i) {
        int idx = tid + i * 256;
        int row = idx >> 6, c4 = idx & 63;
        const ushort4 a = ((const ushort4*)(attnw + (size_t)(mbase + row) * E_))[c4];
        *(ushort4*)&sA[row][c4 * 4] = a;
    }
    __syncthreads();
    const int wave = tid >> 6, lane = tid & 63;
    const int quad = lane >> 4, m16 = lane & 15;

    bf16x8 af[8];
#pragma unroll
    for (int kc = 0; kc < 8; ++kc)
        af[kc] = *(const bf16x8*)&sA[m16][kc * 32 + quad * 8];

#pragma unroll
    for (int i = 0; i < 4; ++i) {
        int nt = wave * 4 + i;
        int ecol = nt * 16 + m16;
        const unsigned short* wrow = Wob + (size_t)ecol * E_;
        floatx4 acc = {0.f, 0.f, 0.f, 0.f};
#pragma unroll
        for (int kc = 0; kc < 8; ++kc) {
            bf16x8 bf = *(const bf16x8*)(wrow + kc * 32 + quad * 8);
            acc = __builtin_amdgcn_mfma_f32_16x16x32_bf16(af[kc], bf, acc, 0, 0, 0);
        }
        float bias = bo[ecol];
        size_t base = (size_t)(mbase + quad * 4) * E_ + ecol;
#pragma unroll
        for (int r = 0; r < 4; ++r)
            out[base + (size_t)r * E_] = acc[r] + bias;
    }
}

extern "C" void kernel_launch(void* const* d_in, const int* in_sizes, int n_in,
                              void* d_out, int out_size, void* d_ws, size_t ws_size,
                              hipStream_t stream) {
    const float* hs   = (const float*)d_in[0];
    const float* oq   = (const float*)d_in[1];
    const float* mask = (const float*)d_in[2];
    const float* Wq   = (const float*)d_in[3];
    const float* bq   = (const float*)d_in[4];
    const float* Wk   = (const float*)d_in[5];
    const float* bk   = (const float*)d_in[6];
    const float* Wv   = (const float*)d_in[7];
    const float* bv   = (const float*)d_in[8];
    const float* Wo   = (const float*)d_in[9];
    const float* bo   = (const float*)d_in[10];
    float* out = (float*)d_out;

    const size_t nBHTD = (size_t)B_ * H_ * T_ * DH_;   // 4,194,304 elems
    unsigned short* Qw    = (unsigned short*)d_ws;
    unsigned short* Kw    = Qw + nBHTD;
    unsigned short* Vtw   = Kw + nBHTD;
    unsigned short* attnw = Vtw + nBHTD;               // 4 x 8 MB
    unsigned short* Wpack = attnw + nBHTD;             // + 512 KB
    int* mask_nz = (int*)(Wpack + 4 * 65536);

    hipMemsetAsync(mask_nz, 0, sizeof(int), stream);
    prepack_kernel<<<128, 256, 0, stream>>>(Wq, Wk, Wv, Wo, Wpack);
    qkvmask_kernel<<<1536 + 2048, 256, 0, stream>>>(
        hs, oq, Wpack, bq, bk, bv, Qw, Kw, Vtw, (const int*)mask, mask_nz);
    attn_kernel<<<B_ * H_ * (T_ / 64), 128, 0, stream>>>(Qw, Kw, Vtw, mask, mask_nz, attnw);
    oproj_kernel<<<(B_ * T_) / 16, 256, 0, stream>>>(attnw, Wpack + 3 * 65536, bo, out);
}

// Round 10
// 379.728 us; speedup vs baseline: 1.0649x; 1.0649x over previous
//
#include <hip/hip_runtime.h>

#define B_ 8
#define T_ 2048
#define E_ 256
#define H_ 8
#define DH_ 32
#define SCALING_ 0.17677669529663687f   // 1/sqrt(32)
#define LOG2E_ 1.4426950408889634f
// Q is pre-scaled by SCALING*log2(e): scores exit QK in log2 domain -> hw exp2
#define QSCALE_ (SCALING_ * LOG2E_)

typedef short bf16x8 __attribute__((ext_vector_type(8)));   // 8 bf16 in 4 VGPRs
typedef float floatx4 __attribute__((ext_vector_type(4)));

__device__ __forceinline__ unsigned short f2bf(float f) {
    union { float f; unsigned u; } v; v.f = f;
    unsigned r = v.u + 0x7FFFu + ((v.u >> 16) & 1u);   // RNE
    return (unsigned short)(r >> 16);
}

// pack 2 f32 -> 2 bf16 (round-half-up) in 3 VALU: add, add, v_perm_b32
__device__ __forceinline__ unsigned pk2(float a, float b) {
    union { float f; unsigned u; } ua, ub;
    ua.f = a; ub.f = b;
    return __builtin_amdgcn_perm(ub.u + 0x8000u, ua.u + 0x8000u, 0x07060302u);
}

__device__ __forceinline__ float fexp2(float x) {
#if __has_builtin(__builtin_amdgcn_exp2f)
    return __builtin_amdgcn_exp2f(x);
#else
    return exp2f(x);
#endif
}

__device__ __forceinline__ bf16x8 pack8(float4 a, float4 b) {
    bf16x8 o;
    o[0] = (short)f2bf(a.x); o[1] = (short)f2bf(a.y);
    o[2] = (short)f2bf(a.z); o[3] = (short)f2bf(a.w);
    o[4] = (short)f2bf(b.x); o[5] = (short)f2bf(b.y);
    o[6] = (short)f2bf(b.z); o[7] = (short)f2bf(b.w);
    return o;
}

// ---------------------------------------------------------------------------
// Kernel 0: weight prepack fp32 -> bf16 (tiny: 128 blocks).
// ---------------------------------------------------------------------------
__global__ __launch_bounds__(256) void prepack_kernel(
    const float* __restrict__ Wq, const float* __restrict__ Wk,
    const float* __restrict__ Wv, const float* __restrict__ Wo,
    unsigned short* __restrict__ Wpack) {
    int idx = blockIdx.x * 256 + threadIdx.x;   // 32768 threads
    int m = idx >> 13;                           // matrix id 0..3
    int e = (idx & 8191) * 8;
    const float* W = (m == 0) ? Wq : (m == 1) ? Wk : (m == 2) ? Wv : Wo;
    float4 a = ((const float4*)(W + e))[0];
    float4 b = ((const float4*)(W + e))[1];
    *(bf16x8*)(Wpack + (size_t)m * 65536 + e) = pack8(a, b);
}

// ---------------------------------------------------------------------------
// Kernel 1: QKV projection (blocks 0..1535) FUSED with mask nonzero check
// (blocks 1536..3583) — the 128 MB mask scan overlaps the GEMM.
// ---------------------------------------------------------------------------
__global__ __launch_bounds__(256, 4) void qkvmask_kernel(
    const float* __restrict__ hs, const float* __restrict__ oq,
    const unsigned short* __restrict__ Wpack,
    const float* __restrict__ bq, const float* __restrict__ bk,
    const float* __restrict__ bv,
    unsigned short* __restrict__ Qw, unsigned short* __restrict__ Kw,
    unsigned short* __restrict__ Vtw,
    const int* __restrict__ mask, int* __restrict__ mask_nz) {
    if (blockIdx.x >= 1536) {
        const size_t n4 = (size_t)B_ * T_ * T_ / 4;   // 8,388,608 int4
        size_t gid = (size_t)(blockIdx.x - 1536) * 256 + threadIdx.x;
        int acc = 0;
        for (size_t i = gid; i < n4; i += (size_t)2048 * 256) {
            int4 v = ((const int4*)mask)[i];
            acc |= v.x | v.y | v.z | v.w;
        }
        if (__builtin_amdgcn_ballot_w64(acc != 0)) {
            if ((threadIdx.x & 63) == 0) atomicOr(mask_nz, 1);
        }
        return;
    }
    __shared__ __align__(16) unsigned short sX[32][264];
    const int mat = blockIdx.x >> 9;          // 0=Q, 1=K, 2=V
    const int mbase = (blockIdx.x & 511) * 32;
    const int b = mbase >> 11, tbase = mbase & 2047;
    const int tid = threadIdx.x;

#pragma unroll
    for (int i = 0; i < 8; ++i) {
        int idx = tid + i * 256;
        int row = idx >> 6, c4 = idx & 63;
        float4 hv = ((const float4*)(hs + (size_t)(mbase + row) * E_))[c4];
        if (mat < 2) {
            float4 ov = ((const float4*)(oq + (size_t)(mbase + row) * E_))[c4];
            hv.x += ov.x; hv.y += ov.y; hv.z += ov.z; hv.w += ov.w;
        }
        ushort4 pb;
        pb.x = f2bf(hv.x); pb.y = f2bf(hv.y); pb.z = f2bf(hv.z); pb.w = f2bf(hv.w);
        *(ushort4*)&sX[row][c4 * 4] = pb;
    }
    __syncthreads();

    const int wave = tid >> 6, lane = tid & 63;
    const int quad = lane >> 4, m16 = lane & 15;
    const unsigned short* W = Wpack + (size_t)mat * 65536;

    bf16x8 xf[2][8];
#pragma unroll
    for (int hgrp = 0; hgrp < 2; ++hgrp)
#pragma unroll
        for (int kc = 0; kc < 8; ++kc)
            xf[hgrp][kc] = *(const bf16x8*)&sX[hgrp * 16 + m16][kc * 32 + quad * 8];

    if (mat < 2) {
        const float* bias = (mat == 0) ? bq : bk;
        unsigned short* Out = (mat == 0) ? Qw : Kw;
#pragma unroll
        for (int i = 0; i < 4; ++i) {
            int nt = wave * 4 + i;
            int ecol = nt * 16 + m16;
            const unsigned short* wrow = W + (size_t)ecol * E_;
            floatx4 acc0 = {0.f, 0.f, 0.f, 0.f};
            floatx4 acc1 = {0.f, 0.f, 0.f, 0.f};
#pragma unroll
            for (int kc = 0; kc < 8; ++kc) {
                bf16x8 bf = *(const bf16x8*)(wrow + kc * 32 + quad * 8);
                acc0 = __builtin_amdgcn_mfma_f32_16x16x32_bf16(xf[0][kc], bf, acc0, 0, 0, 0);
                acc1 = __builtin_amdgcn_mfma_f32_16x16x32_bf16(xf[1][kc], bf, acc1, 0, 0, 0);
            }
            float bs = bias[ecol];
            int h = ecol >> 5, dh = ecol & 31;
            size_t base0 = (((size_t)b * H_ + h) * T_ + (tbase + quad * 4)) * DH_ + dh;
            size_t base1 = base0 + (size_t)16 * DH_;
#pragma unroll
            for (int r = 0; r < 4; ++r) {
                float v0 = acc0[r] + bs, v1 = acc1[r] + bs;
                if (mat == 0) { v0 *= QSCALE_; v1 *= QSCALE_; }
                Out[base0 + (size_t)r * DH_] = f2bf(v0);
                Out[base1 + (size_t)r * DH_] = f2bf(v1);
            }
        }
    } else {
#pragma unroll
        for (int i = 0; i < 4; ++i) {
            int et = wave * 4 + i;
            int erow = et * 16 + m16;
            const unsigned short* wrow = W + (size_t)erow * E_;
            floatx4 acc0 = {0.f, 0.f, 0.f, 0.f};
            floatx4 acc1 = {0.f, 0.f, 0.f, 0.f};
#pragma unroll
            for (int kc = 0; kc < 8; ++kc) {
                bf16x8 wf = *(const bf16x8*)(wrow + kc * 32 + quad * 8);
                acc0 = __builtin_amdgcn_mfma_f32_16x16x32_bf16(wf, xf[0][kc], acc0, 0, 0, 0);
                acc1 = __builtin_amdgcn_mfma_f32_16x16x32_bf16(wf, xf[1][kc], acc1, 0, 0, 0);
            }
            int t0 = tbase + m16, t1 = t0 + 16;
#pragma unroll
            for (int r = 0; r < 4; ++r) {
                int ev = et * 16 + quad * 4 + r;
                int h = ev >> 5, dh = ev & 31;
                size_t vb = (((size_t)b * H_ + h) * DH_ + dh) * T_;
                Vtw[vb + t0] = f2bf(acc0[r] + bv[ev]);
                Vtw[vb + t1] = f2bf(acc1[r] + bv[ev]);
            }
        }
    }
}

// ---------------------------------------------------------------------------
// Kernel 2: flash attention. Proven R6 shell: 256 threads / 4 waves, two
// q-streams per wave, (256,3) — the no-spill configuration (R8/R9's 128-thr
// variants spilled 50-64 MB to scratch). R7's VALU cuts kept (exp2 domain,
// l via ones-MFMA, perm-pack), swizzle dropped (R7: conflicts 6.3->8.4M).
// New vs R6: per-half V prefetch — V b128 loads issue before the softmax so
// their L2 latency hides under QK MFMA + exp2 instead of stalling the PV
// loop. No barriers (sPT per-wave). Grid = B*H*(T/128) = 1024 blocks.
// ---------------------------------------------------------------------------
__global__ __launch_bounds__(256, 3) void attn_kernel(
    const unsigned short* __restrict__ Qw, const unsigned short* __restrict__ Kw,
    const unsigned short* __restrict__ Vtw, const float* __restrict__ mask,
    const int* __restrict__ mask_nz, unsigned short* __restrict__ attnw) {
    __shared__ __align__(16) unsigned short sPT[4][2][16][136];  // [wave][stream][q][key]
    const int tid = threadIdx.x;
    const int wave = tid >> 6, lane = tid & 63;
    const int quad = lane >> 4, m16 = lane & 15;
    const int bh = blockIdx.x & 63, qt = blockIdx.x >> 6;   // bh%8==h -> XCD
    const int b = bh >> 3, h = bh & 7;
    const int qA = qt * 128 + wave * 32;
    const int qB = qA + 16;
    const int mnz = *mask_nz;

    bf16x8 qfragA = *(const bf16x8*)(Qw + ((size_t)bh * T_ + qA + m16) * DH_ + quad * 8);
    bf16x8 qfragB = *(const bf16x8*)(Qw + ((size_t)bh * T_ + qB + m16) * DH_ + quad * 8);
    const unsigned short* Kb = Kw + (size_t)bh * T_ * DH_;
    const unsigned short* Vb = Vtw + (size_t)bh * DH_ * T_;
    const float* MbA = mask + ((size_t)b * T_ + qA + m16) * T_ + quad * 4;
    const float* MbB = MbA + (size_t)16 * T_;

    floatx4 O0A = {0.f, 0.f, 0.f, 0.f}, O1A = {0.f, 0.f, 0.f, 0.f};
    floatx4 O0B = {0.f, 0.f, 0.f, 0.f}, O1B = {0.f, 0.f, 0.f, 0.f};
    floatx4 LA  = {0.f, 0.f, 0.f, 0.f}, LB  = {0.f, 0.f, 0.f, 0.f};
    float mprevA = -1e30f, mprevB = -1e30f;
    const floatx4 zero = {0.f, 0.f, 0.f, 0.f};

    bf16x8 ones8;
#pragma unroll
    for (int i = 0; i < 8; ++i) ones8[i] = (short)0x3F80;   // bf16 1.0

    bf16x8 kf[8];
#pragma unroll
    for (int c = 0; c < 8; ++c)
        kf[c] = *(const bf16x8*)(Kb + (size_t)(c * 16 + m16) * DH_ + quad * 8);

    for (int kt = 0; kt < 16; ++kt) {
        const int s0 = kt * 128;
#pragma unroll
        for (int hf = 0; hf < 2; ++hf) {
            const int cb = hf * 4;
            // V prefetch for this half: issued before the softmax so L2
            // latency hides under QK MFMA + exp2.
            bf16x8 vf0[2], vf1[2];
#pragma unroll
            for (int sb = 0; sb < 2; ++sb) {
                int ko = s0 + (cb + sb * 2) * 16 + quad * 8;
                vf0[sb] = *(const bf16x8*)(Vb + (size_t)m16 * T_ + ko);
                vf1[sb] = *(const bf16x8*)(Vb + (size_t)(16 + m16) * T_ + ko);
            }
            floatx4 scA[4], scB[4];
#pragma unroll
            for (int c = 0; c < 4; ++c) {
                scA[c] = __builtin_amdgcn_mfma_f32_16x16x32_bf16(kf[cb + c], qfragA, zero, 0, 0, 0);
                scB[c] = __builtin_amdgcn_mfma_f32_16x16x32_bf16(kf[cb + c], qfragB, zero, 0, 0, 0);
            }
            if (kt < 15) {
#pragma unroll
                for (int c = 0; c < 4; ++c)
                    kf[cb + c] = *(const bf16x8*)(
                        Kb + (size_t)(s0 + 128 + (cb + c) * 16 + m16) * DH_ + quad * 8);
            }
            if (!mnz) {
                // FAST PATH: raw exp2, perm-pack, LDS. No stats, no adds.
#pragma unroll
                for (int c = 0; c < 4; ++c) {
                    float a0 = fexp2(scA[c][0]), a1 = fexp2(scA[c][1]);
                    float a2 = fexp2(scA[c][2]), a3 = fexp2(scA[c][3]);
                    float b0 = fexp2(scB[c][0]), b1 = fexp2(scB[c][1]);
                    float b2 = fexp2(scB[c][2]), b3 = fexp2(scB[c][3]);
                    uint2 wa = {pk2(a0, a1), pk2(a2, a3)};
                    uint2 wb = {pk2(b0, b1), pk2(b2, b3)};
                    int col = (cb + c) * 16 + quad * 4;
                    *(uint2*)&sPT[wave][0][m16][col] = wa;
                    *(uint2*)&sPT[wave][1][m16][col] = wb;
                }
            } else {
                // SLOW PATH: online softmax in log2 domain; mask * log2e.
#pragma unroll
                for (int c = 0; c < 4; ++c) {
                    float4 ma = *(const float4*)(MbA + s0 + (cb + c) * 16);
                    float4 mb = *(const float4*)(MbB + s0 + (cb + c) * 16);
                    scA[c][0] += ma.x * LOG2E_; scA[c][1] += ma.y * LOG2E_;
                    scA[c][2] += ma.z * LOG2E_; scA[c][3] += ma.w * LOG2E_;
                    scB[c][0] += mb.x * LOG2E_; scB[c][1] += mb.y * LOG2E_;
                    scB[c][2] += mb.z * LOG2E_; scB[c][3] += mb.w * LOG2E_;
                }
                float mlA = -1e30f, mlB = -1e30f;
#pragma unroll
                for (int c = 0; c < 4; ++c) {
                    mlA = fmaxf(fmaxf(fmaxf(scA[c][0], scA[c][1]), fmaxf(scA[c][2], scA[c][3])), mlA);
                    mlB = fmaxf(fmaxf(fmaxf(scB[c][0], scB[c][1]), fmaxf(scB[c][2], scB[c][3])), mlB);
                }
                mlA = fmaxf(mlA, __shfl_xor(mlA, 16, 64));
                mlA = fmaxf(mlA, __shfl_xor(mlA, 32, 64));
                mlB = fmaxf(mlB, __shfl_xor(mlB, 16, 64));
                mlB = fmaxf(mlB, __shfl_xor(mlB, 32, 64));
                float mnA = fmaxf(mprevA, mlA), mnB = fmaxf(mprevB, mlB);
                float alA = fexp2(mprevA - mnA), alB = fexp2(mprevB - mnB);
                mprevA = mnA; mprevB = mnB;
#pragma unroll
                for (int r = 0; r < 4; ++r) {
                    O0A[r] *= alA; O1A[r] *= alA; LA[r] *= alA;
                    O0B[r] *= alB; O1B[r] *= alB; LB[r] *= alB;
                }
#pragma unroll
                for (int c = 0; c < 4; ++c) {
                    float a0 = fexp2(scA[c][0] - mnA), a1 = fexp2(scA[c][1] - mnA);
                    float a2 = fexp2(scA[c][2] - mnA), a3 = fexp2(scA[c][3] - mnA);
                    float b0 = fexp2(scB[c][0] - mnB), b1 = fexp2(scB[c][1] - mnB);
                    float b2 = fexp2(scB[c][2] - mnB), b3 = fexp2(scB[c][3] - mnB);
                    uint2 wa = {pk2(a0, a1), pk2(a2, a3)};
                    uint2 wb = {pk2(b0, b1), pk2(b2, b3)};
                    int col = (cb + c) * 16 + quad * 4;
                    *(uint2*)&sPT[wave][0][m16][col] = wa;
                    *(uint2*)&sPT[wave][1][m16][col] = wb;
                }
            }
            // PV + l for this half; V already in registers (prefetched).
#pragma unroll
            for (int sb = 0; sb < 2; ++sb) {
                int col = (cb + sb * 2) * 16 + quad * 8;
                bf16x8 pbA = *(const bf16x8*)&sPT[wave][0][m16][col];
                bf16x8 pbB = *(const bf16x8*)&sPT[wave][1][m16][col];
                O0A = __builtin_amdgcn_mfma_f32_16x16x32_bf16(vf0[sb], pbA, O0A, 0, 0, 0);
                O0B = __builtin_amdgcn_mfma_f32_16x16x32_bf16(vf0[sb], pbB, O0B, 0, 0, 0);
                O1A = __builtin_amdgcn_mfma_f32_16x16x32_bf16(vf1[sb], pbA, O1A, 0, 0, 0);
                O1B = __builtin_amdgcn_mfma_f32_16x16x32_bf16(vf1[sb], pbB, O1B, 0, 0, 0);
                LA  = __builtin_amdgcn_mfma_f32_16x16x32_bf16(ones8, pbA, LA, 0, 0, 0);
                LB  = __builtin_amdgcn_mfma_f32_16x16x32_bf16(ones8, pbB, LB, 0, 0, 0);
            }
        }
    }
    float invA = 1.0f / LA[0], invB = 1.0f / LB[0];
    size_t obA = ((size_t)b * T_ + qA + m16) * E_ + h * DH_ + quad * 4;
    size_t obB = ((size_t)b * T_ + qB + m16) * E_ + h * DH_ + quad * 4;
    ushort4 sv;
    sv.x = f2bf(O0A[0] * invA); sv.y = f2bf(O0A[1] * invA);
    sv.z = f2bf(O0A[2] * invA); sv.w = f2bf(O0A[3] * invA);
    *(ushort4*)(attnw + obA) = sv;
    sv.x = f2bf(O1A[0] * invA); sv.y = f2bf(O1A[1] * invA);
    sv.z = f2bf(O1A[2] * invA); sv.w = f2bf(O1A[3] * invA);
    *(ushort4*)(attnw + obA + 16) = sv;
    sv.x = f2bf(O0B[0] * invB); sv.y = f2bf(O0B[1] * invB);
    sv.z = f2bf(O0B[2] * invB); sv.w = f2bf(O0B[3] * invB);
    *(ushort4*)(attnw + obB) = sv;
    sv.x = f2bf(O1B[0] * invB); sv.y = f2bf(O1B[1] * invB);
    sv.z = f2bf(O1B[2] * invB); sv.w = f2bf(O1B[3] * invB);
    *(ushort4*)(attnw + obB + 16) = sv;
}

// ---------------------------------------------------------------------------
// Kernel 3: output projection: out = attn @ Wo^T + bo  (fp32 out, bf16 weights)
// ---------------------------------------------------------------------------
__global__ __launch_bounds__(256, 4) void oproj_kernel(
    const unsigned short* __restrict__ attnw, const unsigned short* __restrict__ Wob,
    const float* __restrict__ bo, float* __restrict__ out) {
    __shared__ __align__(16) unsigned short sA[16][264];
    const int tid = threadIdx.x;
    const int mbase = blockIdx.x * 16;
#pragma unroll
    for (int i = 0; i < 4; ++i) {
        int idx = tid + i * 256;
        int row = idx >> 6, c4 = idx & 63;
        const ushort4 a = ((const ushort4*)(attnw + (size_t)(mbase + row) * E_))[c4];
        *(ushort4*)&sA[row][c4 * 4] = a;
    }
    __syncthreads();
    const int wave = tid >> 6, lane = tid & 63;
    const int quad = lane >> 4, m16 = lane & 15;

    bf16x8 af[8];
#pragma unroll
    for (int kc = 0; kc < 8; ++kc)
        af[kc] = *(const bf16x8*)&sA[m16][kc * 32 + quad * 8];

#pragma unroll
    for (int i = 0; i < 4; ++i) {
        int nt = wave * 4 + i;
        int ecol = nt * 16 + m16;
        const unsigned short* wrow = Wob + (size_t)ecol * E_;
        floatx4 acc = {0.f, 0.f, 0.f, 0.f};
#pragma unroll
        for (int kc = 0; kc < 8; ++kc) {
            bf16x8 bf = *(const bf16x8*)(wrow + kc * 32 + quad * 8);
            acc = __builtin_amdgcn_mfma_f32_16x16x32_bf16(af[kc], bf, acc, 0, 0, 0);
        }
        float bias = bo[ecol];
        size_t base = (size_t)(mbase + quad * 4) * E_ + ecol;
#pragma unroll
        for (int r = 0; r < 4; ++r)
            out[base + (size_t)r * E_] = acc[r] + bias;
    }
}

extern "C" void kernel_launch(void* const* d_in, const int* in_sizes, int n_in,
                              void* d_out, int out_size, void* d_ws, size_t ws_size,
                              hipStream_t stream) {
    const float* hs   = (const float*)d_in[0];
    const float* oq   = (const float*)d_in[1];
    const float* mask = (const float*)d_in[2];
    const float* Wq   = (const float*)d_in[3];
    const float* bq   = (const float*)d_in[4];
    const float* Wk   = (const float*)d_in[5];
    const float* bk   = (const float*)d_in[6];
    const float* Wv   = (const float*)d_in[7];
    const float* bv   = (const float*)d_in[8];
    const float* Wo   = (const float*)d_in[9];
    const float* bo   = (const float*)d_in[10];
    float* out = (float*)d_out;

    const size_t nBHTD = (size_t)B_ * H_ * T_ * DH_;   // 4,194,304 elems
    unsigned short* Qw    = (unsigned short*)d_ws;
    unsigned short* Kw    = Qw + nBHTD;
    unsigned short* Vtw   = Kw + nBHTD;
    unsigned short* attnw = Vtw + nBHTD;               // 4 x 8 MB
    unsigned short* Wpack = attnw + nBHTD;             // + 512 KB
    int* mask_nz = (int*)(Wpack + 4 * 65536);

    hipMemsetAsync(mask_nz, 0, sizeof(int), stream);
    prepack_kernel<<<128, 256, 0, stream>>>(Wq, Wk, Wv, Wo, Wpack);
    qkvmask_kernel<<<1536 + 2048, 256, 0, stream>>>(
        hs, oq, Wpack, bq, bk, bv, Qw, Kw, Vtw, (const int*)mask, mask_nz);
    attn_kernel<<<B_ * H_ * (T_ / 128), 256, 0, stream>>>(Qw, Kw, Vtw, mask, mask_nz, attnw);
    oproj_kernel<<<(B_ * T_) / 16, 256, 0, stream>>>(attnw, Wpack + 3 * 65536, bo, out);
}

// Round 11
// 370.564 us; speedup vs baseline: 1.0912x; 1.0247x over previous
//
#include <hip/hip_runtime.h>

#define B_ 8
#define T_ 2048
#define E_ 256
#define H_ 8
#define DH_ 32
#define SCALING_ 0.17677669529663687f   // 1/sqrt(32)
#define LOG2E_ 1.4426950408889634f
// Q is pre-scaled by SCALING*log2(e): scores exit QK in log2 domain -> hw exp2
#define QSCALE_ (SCALING_ * LOG2E_)

typedef short bf16x8 __attribute__((ext_vector_type(8)));   // 8 bf16 in 4 VGPRs
typedef float floatx4 __attribute__((ext_vector_type(4)));

__device__ __forceinline__ unsigned short f2bf(float f) {
    union { float f; unsigned u; } v; v.f = f;
    unsigned r = v.u + 0x7FFFu + ((v.u >> 16) & 1u);   // RNE
    return (unsigned short)(r >> 16);
}

// pack 2 f32 -> 2 bf16 (round-half-up) in 3 VALU: add, add, v_perm_b32
__device__ __forceinline__ unsigned pk2(float a, float b) {
    union { float f; unsigned u; } ua, ub;
    ua.f = a; ub.f = b;
    return __builtin_amdgcn_perm(ub.u + 0x8000u, ua.u + 0x8000u, 0x07060302u);
}

__device__ __forceinline__ float fexp2(float x) {
#if __has_builtin(__builtin_amdgcn_exp2f)
    return __builtin_amdgcn_exp2f(x);
#else
    return exp2f(x);
#endif
}

__device__ __forceinline__ bf16x8 pack8(float4 a, float4 b) {
    bf16x8 o;
    o[0] = (short)f2bf(a.x); o[1] = (short)f2bf(a.y);
    o[2] = (short)f2bf(a.z); o[3] = (short)f2bf(a.w);
    o[4] = (short)f2bf(b.x); o[5] = (short)f2bf(b.y);
    o[6] = (short)f2bf(b.z); o[7] = (short)f2bf(b.w);
    return o;
}

// ---------------------------------------------------------------------------
// Kernel 0: weight prepack fp32 -> bf16; block 0 zeroes the mask flag
// (this dispatch completes before qkvmask's scan starts on the same stream).
// ---------------------------------------------------------------------------
__global__ __launch_bounds__(256) void prepack_kernel(
    const float* __restrict__ Wq, const float* __restrict__ Wk,
    const float* __restrict__ Wv, const float* __restrict__ Wo,
    unsigned short* __restrict__ Wpack, int* __restrict__ mask_nz) {
    if (blockIdx.x == 0 && threadIdx.x == 0) *mask_nz = 0;
    int idx = blockIdx.x * 256 + threadIdx.x;   // 32768 threads
    int m = idx >> 13;                           // matrix id 0..3
    int e = (idx & 8191) * 8;
    const float* W = (m == 0) ? Wq : (m == 1) ? Wk : (m == 2) ? Wv : Wo;
    float4 a = ((const float4*)(W + e))[0];
    float4 b = ((const float4*)(W + e))[1];
    *(bf16x8*)(Wpack + (size_t)m * 65536 + e) = pack8(a, b);
}

// ---------------------------------------------------------------------------
// Kernel 1: QKV projection (blocks 0..1535) FUSED with mask nonzero check
// (blocks 1536..3583) — the 128 MB mask scan overlaps the GEMM.
// ---------------------------------------------------------------------------
__global__ __launch_bounds__(256, 4) void qkvmask_kernel(
    const float* __restrict__ hs, const float* __restrict__ oq,
    const unsigned short* __restrict__ Wpack,
    const float* __restrict__ bq, const float* __restrict__ bk,
    const float* __restrict__ bv,
    unsigned short* __restrict__ Qw, unsigned short* __restrict__ Kw,
    unsigned short* __restrict__ Vtw,
    const int* __restrict__ mask, int* __restrict__ mask_nz) {
    if (blockIdx.x >= 1536) {
        const size_t n4 = (size_t)B_ * T_ * T_ / 4;   // 8,388,608 int4
        size_t gid = (size_t)(blockIdx.x - 1536) * 256 + threadIdx.x;
        int acc = 0;
        for (size_t i = gid; i < n4; i += (size_t)2048 * 256) {
            int4 v = ((const int4*)mask)[i];
            acc |= v.x | v.y | v.z | v.w;
        }
        if (__builtin_amdgcn_ballot_w64(acc != 0)) {
            if ((threadIdx.x & 63) == 0) atomicOr(mask_nz, 1);
        }
        return;
    }
    __shared__ __align__(16) unsigned short sX[32][264];
    const int mat = blockIdx.x >> 9;          // 0=Q, 1=K, 2=V
    const int mbase = (blockIdx.x & 511) * 32;
    const int b = mbase >> 11, tbase = mbase & 2047;
    const int tid = threadIdx.x;

#pragma unroll
    for (int i = 0; i < 8; ++i) {
        int idx = tid + i * 256;
        int row = idx >> 6, c4 = idx & 63;
        float4 hv = ((const float4*)(hs + (size_t)(mbase + row) * E_))[c4];
        if (mat < 2) {
            float4 ov = ((const float4*)(oq + (size_t)(mbase + row) * E_))[c4];
            hv.x += ov.x; hv.y += ov.y; hv.z += ov.z; hv.w += ov.w;
        }
        ushort4 pb;
        pb.x = f2bf(hv.x); pb.y = f2bf(hv.y); pb.z = f2bf(hv.z); pb.w = f2bf(hv.w);
        *(ushort4*)&sX[row][c4 * 4] = pb;
    }
    __syncthreads();

    const int wave = tid >> 6, lane = tid & 63;
    const int quad = lane >> 4, m16 = lane & 15;
    const unsigned short* W = Wpack + (size_t)mat * 65536;

    bf16x8 xf[2][8];
#pragma unroll
    for (int hgrp = 0; hgrp < 2; ++hgrp)
#pragma unroll
        for (int kc = 0; kc < 8; ++kc)
            xf[hgrp][kc] = *(const bf16x8*)&sX[hgrp * 16 + m16][kc * 32 + quad * 8];

    if (mat < 2) {
        const float* bias = (mat == 0) ? bq : bk;
        unsigned short* Out = (mat == 0) ? Qw : Kw;
#pragma unroll
        for (int i = 0; i < 4; ++i) {
            int nt = wave * 4 + i;
            int ecol = nt * 16 + m16;
            const unsigned short* wrow = W + (size_t)ecol * E_;
            floatx4 acc0 = {0.f, 0.f, 0.f, 0.f};
            floatx4 acc1 = {0.f, 0.f, 0.f, 0.f};
#pragma unroll
            for (int kc = 0; kc < 8; ++kc) {
                bf16x8 bf = *(const bf16x8*)(wrow + kc * 32 + quad * 8);
                acc0 = __builtin_amdgcn_mfma_f32_16x16x32_bf16(xf[0][kc], bf, acc0, 0, 0, 0);
                acc1 = __builtin_amdgcn_mfma_f32_16x16x32_bf16(xf[1][kc], bf, acc1, 0, 0, 0);
            }
            float bs = bias[ecol];
            int h = ecol >> 5, dh = ecol & 31;
            size_t base0 = (((size_t)b * H_ + h) * T_ + (tbase + quad * 4)) * DH_ + dh;
            size_t base1 = base0 + (size_t)16 * DH_;
#pragma unroll
            for (int r = 0; r < 4; ++r) {
                float v0 = acc0[r] + bs, v1 = acc1[r] + bs;
                if (mat == 0) { v0 *= QSCALE_; v1 *= QSCALE_; }
                Out[base0 + (size_t)r * DH_] = f2bf(v0);
                Out[base1 + (size_t)r * DH_] = f2bf(v1);
            }
        }
    } else {
#pragma unroll
        for (int i = 0; i < 4; ++i) {
            int et = wave * 4 + i;
            int erow = et * 16 + m16;
            const unsigned short* wrow = W + (size_t)erow * E_;
            floatx4 acc0 = {0.f, 0.f, 0.f, 0.f};
            floatx4 acc1 = {0.f, 0.f, 0.f, 0.f};
#pragma unroll
            for (int kc = 0; kc < 8; ++kc) {
                bf16x8 wf = *(const bf16x8*)(wrow + kc * 32 + quad * 8);
                acc0 = __builtin_amdgcn_mfma_f32_16x16x32_bf16(wf, xf[0][kc], acc0, 0, 0, 0);
                acc1 = __builtin_amdgcn_mfma_f32_16x16x32_bf16(wf, xf[1][kc], acc1, 0, 0, 0);
            }
            int t0 = tbase + m16, t1 = t0 + 16;
#pragma unroll
            for (int r = 0; r < 4; ++r) {
                int ev = et * 16 + quad * 4 + r;
                int h = ev >> 5, dh = ev & 31;
                size_t vb = (((size_t)b * H_ + h) * DH_ + dh) * T_;
                Vtw[vb + t0] = f2bf(acc0[r] + bv[ev]);
                Vtw[vb + t1] = f2bf(acc1[r] + bv[ev]);
            }
        }
    }
}

// ---------------------------------------------------------------------------
// Kernel 2: flash attention. R10 core (best measured: 256 thr / 4 waves /
// 2 q-streams / (256,3) no-spill / exp2 domain / ones-MFMA l / perm-pack /
// per-half V prefetch). Change vs R10: sPT split into per-HALF buffers so
// half-1's QK/exp cannot alias half-0's P reads — removes the false LDS
// dependence between halves and lets the scheduler overlap them.
// No barriers (sPT per-wave). Grid = B*H*(T/128) = 1024 blocks.
// ---------------------------------------------------------------------------
__global__ __launch_bounds__(256, 3) void attn_kernel(
    const unsigned short* __restrict__ Qw, const unsigned short* __restrict__ Kw,
    const unsigned short* __restrict__ Vtw, const float* __restrict__ mask,
    const int* __restrict__ mask_nz, unsigned short* __restrict__ attnw) {
    // [wave][half][stream][q][key-in-half], stride 72 shorts = 144 B
    __shared__ __align__(16) unsigned short sPT[4][2][2][16][72];
    const int tid = threadIdx.x;
    const int wave = tid >> 6, lane = tid & 63;
    const int quad = lane >> 4, m16 = lane & 15;
    const int bh = blockIdx.x & 63, qt = blockIdx.x >> 6;   // bh%8==h -> XCD
    const int b = bh >> 3, h = bh & 7;
    const int qA = qt * 128 + wave * 32;
    const int qB = qA + 16;

    bf16x8 qfragA = *(const bf16x8*)(Qw + ((size_t)bh * T_ + qA + m16) * DH_ + quad * 8);
    bf16x8 qfragB = *(const bf16x8*)(Qw + ((size_t)bh * T_ + qB + m16) * DH_ + quad * 8);
    const unsigned short* Kb = Kw + (size_t)bh * T_ * DH_;
    const unsigned short* Vb = Vtw + (size_t)bh * DH_ * T_;
    const float* MbA = mask + ((size_t)b * T_ + qA + m16) * T_ + quad * 4;
    const float* MbB = MbA + (size_t)16 * T_;

    floatx4 O0A = {0.f, 0.f, 0.f, 0.f}, O1A = {0.f, 0.f, 0.f, 0.f};
    floatx4 O0B = {0.f, 0.f, 0.f, 0.f}, O1B = {0.f, 0.f, 0.f, 0.f};
    floatx4 LA  = {0.f, 0.f, 0.f, 0.f}, LB  = {0.f, 0.f, 0.f, 0.f};
    float mprevA = -1e30f, mprevB = -1e30f;
    const floatx4 zero = {0.f, 0.f, 0.f, 0.f};

    bf16x8 ones8;
#pragma unroll
    for (int i = 0; i < 8; ++i) ones8[i] = (short)0x3F80;   // bf16 1.0

    bf16x8 kf[8];
#pragma unroll
    for (int c = 0; c < 8; ++c)
        kf[c] = *(const bf16x8*)(Kb + (size_t)(c * 16 + m16) * DH_ + quad * 8);

    const int mnz = *mask_nz;   // after prefetch issues

    for (int kt = 0; kt < 16; ++kt) {
        const int s0 = kt * 128;
#pragma unroll
        for (int hf = 0; hf < 2; ++hf) {
            const int cb = hf * 4;
            // V prefetch for this half: issued before the softmax so L2
            // latency hides under QK MFMA + exp2.
            bf16x8 vf0[2], vf1[2];
#pragma unroll
            for (int sb = 0; sb < 2; ++sb) {
                int ko = s0 + (cb + sb * 2) * 16 + quad * 8;
                vf0[sb] = *(const bf16x8*)(Vb + (size_t)m16 * T_ + ko);
                vf1[sb] = *(const bf16x8*)(Vb + (size_t)(16 + m16) * T_ + ko);
            }
            floatx4 scA[4], scB[4];
#pragma unroll
            for (int c = 0; c < 4; ++c) {
                scA[c] = __builtin_amdgcn_mfma_f32_16x16x32_bf16(kf[cb + c], qfragA, zero, 0, 0, 0);
                scB[c] = __builtin_amdgcn_mfma_f32_16x16x32_bf16(kf[cb + c], qfragB, zero, 0, 0, 0);
            }
            if (kt < 15) {
#pragma unroll
                for (int c = 0; c < 4; ++c)
                    kf[cb + c] = *(const bf16x8*)(
                        Kb + (size_t)(s0 + 128 + (cb + c) * 16 + m16) * DH_ + quad * 8);
            }
            if (!mnz) {
                // FAST PATH: raw exp2, perm-pack, LDS. No stats, no adds.
#pragma unroll
                for (int c = 0; c < 4; ++c) {
                    float a0 = fexp2(scA[c][0]), a1 = fexp2(scA[c][1]);
                    float a2 = fexp2(scA[c][2]), a3 = fexp2(scA[c][3]);
                    float b0 = fexp2(scB[c][0]), b1 = fexp2(scB[c][1]);
                    float b2 = fexp2(scB[c][2]), b3 = fexp2(scB[c][3]);
                    uint2 wa = {pk2(a0, a1), pk2(a2, a3)};
                    uint2 wb = {pk2(b0, b1), pk2(b2, b3)};
                    int col = c * 16 + quad * 4;
                    *(uint2*)&sPT[wave][hf][0][m16][col] = wa;
                    *(uint2*)&sPT[wave][hf][1][m16][col] = wb;
                }
            } else {
                // SLOW PATH: online softmax in log2 domain; mask * log2e.
#pragma unroll
                for (int c = 0; c < 4; ++c) {
                    float4 ma = *(const float4*)(MbA + s0 + (cb + c) * 16);
                    float4 mb = *(const float4*)(MbB + s0 + (cb + c) * 16);
                    scA[c][0] += ma.x * LOG2E_; scA[c][1] += ma.y * LOG2E_;
                    scA[c][2] += ma.z * LOG2E_; scA[c][3] += ma.w * LOG2E_;
                    scB[c][0] += mb.x * LOG2E_; scB[c][1] += mb.y * LOG2E_;
                    scB[c][2] += mb.z * LOG2E_; scB[c][3] += mb.w * LOG2E_;
                }
                float mlA = -1e30f, mlB = -1e30f;
#pragma unroll
                for (int c = 0; c < 4; ++c) {
                    mlA = fmaxf(fmaxf(fmaxf(scA[c][0], scA[c][1]), fmaxf(scA[c][2], scA[c][3])), mlA);
                    mlB = fmaxf(fmaxf(fmaxf(scB[c][0], scB[c][1]), fmaxf(scB[c][2], scB[c][3])), mlB);
                }
                mlA = fmaxf(mlA, __shfl_xor(mlA, 16, 64));
                mlA = fmaxf(mlA, __shfl_xor(mlA, 32, 64));
                mlB = fmaxf(mlB, __shfl_xor(mlB, 16, 64));
                mlB = fmaxf(mlB, __shfl_xor(mlB, 32, 64));
                float mnA = fmaxf(mprevA, mlA), mnB = fmaxf(mprevB, mlB);
                float alA = fexp2(mprevA - mnA), alB = fexp2(mprevB - mnB);
                mprevA = mnA; mprevB = mnB;
#pragma unroll
                for (int r = 0; r < 4; ++r) {
                    O0A[r] *= alA; O1A[r] *= alA; LA[r] *= alA;
                    O0B[r] *= alB; O1B[r] *= alB; LB[r] *= alB;
                }
#pragma unroll
                for (int c = 0; c < 4; ++c) {
                    float a0 = fexp2(scA[c][0] - mnA), a1 = fexp2(scA[c][1] - mnA);
                    float a2 = fexp2(scA[c][2] - mnA), a3 = fexp2(scA[c][3] - mnA);
                    float b0 = fexp2(scB[c][0] - mnB), b1 = fexp2(scB[c][1] - mnB);
                    float b2 = fexp2(scB[c][2] - mnB), b3 = fexp2(scB[c][3] - mnB);
                    uint2 wa = {pk2(a0, a1), pk2(a2, a3)};
                    uint2 wb = {pk2(b0, b1), pk2(b2, b3)};
                    int col = c * 16 + quad * 4;
                    *(uint2*)&sPT[wave][hf][0][m16][col] = wa;
                    *(uint2*)&sPT[wave][hf][1][m16][col] = wb;
                }
            }
            // PV + l for this half; V already in registers (prefetched).
#pragma unroll
            for (int sb = 0; sb < 2; ++sb) {
                int col = sb * 32 + quad * 8;
                bf16x8 pbA = *(const bf16x8*)&sPT[wave][hf][0][m16][col];
                bf16x8 pbB = *(const bf16x8*)&sPT[wave][hf][1][m16][col];
                O0A = __builtin_amdgcn_mfma_f32_16x16x32_bf16(vf0[sb], pbA, O0A, 0, 0, 0);
                O0B = __builtin_amdgcn_mfma_f32_16x16x32_bf16(vf0[sb], pbB, O0B, 0, 0, 0);
                O1A = __builtin_amdgcn_mfma_f32_16x16x32_bf16(vf1[sb], pbA, O1A, 0, 0, 0);
                O1B = __builtin_amdgcn_mfma_f32_16x16x32_bf16(vf1[sb], pbB, O1B, 0, 0, 0);
                LA  = __builtin_amdgcn_mfma_f32_16x16x32_bf16(ones8, pbA, LA, 0, 0, 0);
                LB  = __builtin_amdgcn_mfma_f32_16x16x32_bf16(ones8, pbB, LB, 0, 0, 0);
            }
        }
    }
    float invA = 1.0f / LA[0], invB = 1.0f / LB[0];
    size_t obA = ((size_t)b * T_ + qA + m16) * E_ + h * DH_ + quad * 4;
    size_t obB = ((size_t)b * T_ + qB + m16) * E_ + h * DH_ + quad * 4;
    ushort4 sv;
    sv.x = f2bf(O0A[0] * invA); sv.y = f2bf(O0A[1] * invA);
    sv.z = f2bf(O0A[2] * invA); sv.w = f2bf(O0A[3] * invA);
    *(ushort4*)(attnw + obA) = sv;
    sv.x = f2bf(O1A[0] * invA); sv.y = f2bf(O1A[1] * invA);
    sv.z = f2bf(O1A[2] * invA); sv.w = f2bf(O1A[3] * invA);
    *(ushort4*)(attnw + obA + 16) = sv;
    sv.x = f2bf(O0B[0] * invB); sv.y = f2bf(O0B[1] * invB);
    sv.z = f2bf(O0B[2] * invB); sv.w = f2bf(O0B[3] * invB);
    *(ushort4*)(attnw + obB) = sv;
    sv.x = f2bf(O1B[0] * invB); sv.y = f2bf(O1B[1] * invB);
    sv.z = f2bf(O1B[2] * invB); sv.w = f2bf(O1B[3] * invB);
    *(ushort4*)(attnw + obB + 16) = sv;
}

// ---------------------------------------------------------------------------
// Kernel 3: output projection: out = attn @ Wo^T + bo  (fp32 out, bf16 weights)
// 512 blocks x 32 rows (2 row-groups/wave) — halves redundant Wo L2 reads.
// ---------------------------------------------------------------------------
__global__ __launch_bounds__(256, 4) void oproj_kernel(
    const unsigned short* __restrict__ attnw, const unsigned short* __restrict__ Wob,
    const float* __restrict__ bo, float* __restrict__ out) {
    __shared__ __align__(16) unsigned short sA[32][264];
    const int tid = threadIdx.x;
    const int mbase = blockIdx.x * 32;
#pragma unroll
    for (int i = 0; i < 8; ++i) {
        int idx = tid + i * 256;
        int row = idx >> 6, c4 = idx & 63;
        const ushort4 a = ((const ushort4*)(attnw + (size_t)(mbase + row) * E_))[c4];
        *(ushort4*)&sA[row][c4 * 4] = a;
    }
    __syncthreads();
    const int wave = tid >> 6, lane = tid & 63;
    const int quad = lane >> 4, m16 = lane & 15;

    bf16x8 af[2][8];
#pragma unroll
    for (int hgrp = 0; hgrp < 2; ++hgrp)
#pragma unroll
        for (int kc = 0; kc < 8; ++kc)
            af[hgrp][kc] = *(const bf16x8*)&sA[hgrp * 16 + m16][kc * 32 + quad * 8];

#pragma unroll
    for (int i = 0; i < 4; ++i) {
        int nt = wave * 4 + i;
        int ecol = nt * 16 + m16;
        const unsigned short* wrow = Wob + (size_t)ecol * E_;
        floatx4 acc0 = {0.f, 0.f, 0.f, 0.f};
        floatx4 acc1 = {0.f, 0.f, 0.f, 0.f};
#pragma unroll
        for (int kc = 0; kc < 8; ++kc) {
            bf16x8 bf = *(const bf16x8*)(wrow + kc * 32 + quad * 8);
            acc0 = __builtin_amdgcn_mfma_f32_16x16x32_bf16(af[0][kc], bf, acc0, 0, 0, 0);
            acc1 = __builtin_amdgcn_mfma_f32_16x16x32_bf16(af[1][kc], bf, acc1, 0, 0, 0);
        }
        float bias = bo[ecol];
        size_t base0 = (size_t)(mbase + quad * 4) * E_ + ecol;
        size_t base1 = base0 + (size_t)16 * E_;
#pragma unroll
        for (int r = 0; r < 4; ++r) {
            out[base0 + (size_t)r * E_] = acc0[r] + bias;
            out[base1 + (size_t)r * E_] = acc1[r] + bias;
        }
    }
}

extern "C" void kernel_launch(void* const* d_in, const int* in_sizes, int n_in,
                              void* d_out, int out_size, void* d_ws, size_t ws_size,
                              hipStream_t stream) {
    const float* hs   = (const float*)d_in[0];
    const float* oq   = (const float*)d_in[1];
    const float* mask = (const float*)d_in[2];
    const float* Wq   = (const float*)d_in[3];
    const float* bq   = (const float*)d_in[4];
    const float* Wk   = (const float*)d_in[5];
    const float* bk   = (const float*)d_in[6];
    const float* Wv   = (const float*)d_in[7];
    const float* bv   = (const float*)d_in[8];
    const float* Wo   = (const float*)d_in[9];
    const float* bo   = (const float*)d_in[10];
    float* out = (float*)d_out;

    const size_t nBHTD = (size_t)B_ * H_ * T_ * DH_;   // 4,194,304 elems
    unsigned short* Qw    = (unsigned short*)d_ws;
    unsigned short* Kw    = Qw + nBHTD;
    unsigned short* Vtw   = Kw + nBHTD;
    unsigned short* attnw = Vtw + nBHTD;               // 4 x 8 MB
    unsigned short* Wpack = attnw + nBHTD;             // + 512 KB
    int* mask_nz = (int*)(Wpack + 4 * 65536);

    prepack_kernel<<<128, 256, 0, stream>>>(Wq, Wk, Wv, Wo, Wpack, mask_nz);
    qkvmask_kernel<<<1536 + 2048, 256, 0, stream>>>(
        hs, oq, Wpack, bq, bk, bv, Qw, Kw, Vtw, (const int*)mask, mask_nz);
    attn_kernel<<<B_ * H_ * (T_ / 128), 256, 0, stream>>>(Qw, Kw, Vtw, mask, mask_nz, attnw);
    oproj_kernel<<<(B_ * T_) / 32, 256, 0, stream>>>(attnw, Wpack + 3 * 65536, bo, out);
}